// Round 4
// baseline (258.325 us; speedup 1.0000x reference)
//
#include <hip/hip_runtime.h>
#include <hip/hip_bf16.h>
#include <cstddef>

#define T_DIM 2048
#define B_DIM 64
#define I_DIM 128
#define H_DIM 128
#define FC_DIM 32
#define O_DIM 2

#define NC 32                // time chunks (parallel affine scan)
#define TC (T_DIM / NC)      // 64 timesteps per chunk
#define MT 4                 // 4 m-tiles of 16 t per chunk
#define CPB 2                // chunks per block -> grid 1024 = 4 blocks/CU,
                             // 32 waves/CU (8/SIMD): full residency

#define LOG2E  1.44269504088896f
#define LOG2E2 2.88539008177793f

typedef __attribute__((ext_vector_type(8))) short bf16x8;
typedef __attribute__((ext_vector_type(4))) float f32x4;

// packed fp32x8 -> bf16x8 (RNE) via v_cvt_pk_bf16_f32
__device__ __forceinline__ bf16x8 cvt8(const float* __restrict__ p) {
    union { bf16x8 v; __hip_bfloat162 h2[4]; } u;
#pragma unroll
    for (int j = 0; j < 4; ++j) {
        float2 f2 = {p[2 * j], p[2 * j + 1]};
        u.h2[j] = __float22bfloat162_rn(f2);
    }
    return u.v;
}

// Pass 0: gate weights fp32 -> bf16, pre-scaled by log2e factors so the
// gates kernel can use exp2 directly. Layout preserved [b][h][i].
__global__ void convert_w_kernel(const float* __restrict__ wg,
                                 const float* __restrict__ wi,
                                 const float* __restrict__ wf,
                                 short* __restrict__ og,
                                 short* __restrict__ oi,
                                 short* __restrict__ of)
{
    const float* src = (blockIdx.y == 0) ? wg : (blockIdx.y == 1) ? wi : wf;
    short* dst       = (blockIdx.y == 0) ? og : (blockIdx.y == 1) ? oi : of;
    const float scale = (blockIdx.y == 0) ? LOG2E2 : LOG2E;
    const size_t idx = ((size_t)blockIdx.x * 256 + threadIdx.x) * 8;
    float4 u0 = *(const float4*)(src + idx);
    float4 u1 = *(const float4*)(src + idx + 4);
    float a[8] = {u0.x * scale, u0.y * scale, u0.z * scale, u0.w * scale,
                  u1.x * scale, u1.y * scale, u1.z * scale, u1.w * scale};
    *(bf16x8*)(dst + idx) = cvt8(a);
}

// Pass 1: one block per (b, chunk-pair), 8 waves covering all 128 h.
// Grid = 1024 = 4 blocks/CU x 8 waves = 32 waves/CU = FULL residency
// (8192 waves = 256 CU x 32). VGPR<=64 enforced via launch_bounds(512,8);
// LDS 4 x 32 KB = 128 <= 160 KB. TLP (not intra-wave ILP) is what hides the
// weight-prologue chain, LDS->MFMA waits, trans-pipe stalls, and the serial
// scan chain -- R1's occupancy counter (34%) identified residency as the
// limiter; R2/R3's ILP-only pipelining moved little.
// Double-buffered LDS frags -> ONE barrier per chunk:
//   iter j: issue x loads for chunk c+1 (px regs)
//           compute chunk c from frag[j&1]        (global latency hides here)
//           cvt+write px -> frag[(j+1)&1]         (its readers done at barrier j-1)
//           barrier                               (publishes frag[(j+1)&1])
// Stage duty: wave w handles m-tile (w>>1), kk pair (w&1)*2+{0,1} -> px = 16 VGPR.
// m-row -> t map within chunk: t = (m>>2)*16 + mt*4 + (m&3); D rows
// (row = quad*4 + r) give quad q the t-range [q*16, q*16+16).
__global__ __launch_bounds__(512, 8)
void gates_scan_kernel(const float* __restrict__ x,
    const short* __restrict__ wg, const short* __restrict__ wi,
    const short* __restrict__ wf,
    const float* __restrict__ b_g, const float* __restrict__ b_i,
    const float* __restrict__ b_f,
    float* __restrict__ wsF, float* __restrict__ wsA)
{
    // frag[buf][mt][kk][lane][8 shorts] = 2 * 4*4*64*8 shorts = 2 * 16 KB
    __shared__ short frag[2][MT * 4 * 64 * 8];

    const int L    = threadIdx.x & 63;
    const int wv   = threadIdx.x >> 6;   // 0..7
    const int col  = L & 15;
    const int quad = L >> 4;
    const int bid  = blockIdx.x;
    const int b    = bid & (B_DIM - 1);  // b-minor: same-b blocks -> same XCD
    const int cp   = bid >> 6;           // 0..15 chunk-pair index

    // stage duty for this wave
    const int mt_s = wv >> 1;            // m-tile staged by this wave
    const int kk0  = (wv & 1) * 2;       // first of 2 kk slices
    const int tl_s = (col >> 2) * 16 + mt_s * 4 + (col & 3);  // t within chunk

    // ---- weight fragments for this wave's 16 h columns: h = wv*16 + col
    const int h = wv * 16 + col;
    bf16x8 Bg[4], Bi[4], Bf[4];
    {
        const size_t wo = ((size_t)b * H_DIM + h) * I_DIM + quad * 8;
#pragma unroll
        for (int kk = 0; kk < 4; ++kk) {
            Bg[kk] = *(const bf16x8*)(wg + wo + kk * 32);
            Bi[kk] = *(const bf16x8*)(wi + wo + kk * 32);
            Bf[kk] = *(const bf16x8*)(wf + wo + kk * 32);
        }
    }
    const float biasg = b_g[b * H_DIM + h] * LOG2E2;
    const float biasi = b_i[b * H_DIM + h] * LOG2E;
    const float biasf = b_f[b * H_DIM + h] * LOG2E;

    // ---- prologue: stage chunk cp*CPB into frag[0]
    {
        const float* xp = x + ((size_t)(cp * CPB * TC + tl_s) * B_DIM + b) * I_DIM;
#pragma unroll
        for (int kq = 0; kq < 2; ++kq) {
            const int kk = kk0 + kq;
            const int i0 = quad * 8 + kk * 32;
            float4 u0 = *(const float4*)(xp + i0);
            float4 u1 = *(const float4*)(xp + i0 + 4);
            float a[8] = {u0.x, u0.y, u0.z, u0.w, u1.x, u1.y, u1.z, u1.w};
            *(bf16x8*)(&frag[0][(((mt_s * 4 + kk) * 64) + L) * 8]) = cvt8(a);
        }
    }
    __syncthreads();

    float4 px[4];  // in-flight x for next chunk (16 VGPRs)

#pragma unroll
    for (int j = 0; j < CPB; ++j) {
        const int c = cp * CPB + j;
        const short* fr = frag[j & 1];

        // issue next chunk's x loads EARLY -> latency hides under compute
        if (j + 1 < CPB) {
            const float* xp = x + ((size_t)((c + 1) * TC + tl_s) * B_DIM + b) * I_DIM;
#pragma unroll
            for (int kq = 0; kq < 2; ++kq) {
                const int i0 = quad * 8 + (kk0 + kq) * 32;
                px[2 * kq]     = *(const float4*)(xp + i0);
                px[2 * kq + 1] = *(const float4*)(xp + i0 + 4);
            }
        }

        // ---- compute chunk c: MFMA + activations + per-quad scan
        float Fq = 1.0f, Aq = 0.0f;
#pragma unroll
        for (int mt = 0; mt < MT; ++mt) {
            bf16x8 ah[4];
#pragma unroll
            for (int kk = 0; kk < 4; ++kk)
                ah[kk] = *(const bf16x8*)(fr + (((mt * 4 + kk) * 64) + L) * 8);
            f32x4 accg = {0.f, 0.f, 0.f, 0.f};
            f32x4 acci = {0.f, 0.f, 0.f, 0.f};
            f32x4 accf = {0.f, 0.f, 0.f, 0.f};
#pragma unroll
            for (int kk = 0; kk < 4; ++kk) {
                accg = __builtin_amdgcn_mfma_f32_16x16x32_bf16(ah[kk], Bg[kk], accg, 0, 0, 0);
                acci = __builtin_amdgcn_mfma_f32_16x16x32_bf16(ah[kk], Bi[kk], acci, 0, 0, 0);
                accf = __builtin_amdgcn_mfma_f32_16x16x32_bf16(ah[kk], Bf[kk], accf, 0, 0, 0);
            }
            // D row = quad*4 + r -> t = quad*16 + mt*4 + r (consecutive per quad)
#pragma unroll
            for (int r = 0; r < 4; ++r) {
                // preacts pre-scaled by log2e (g by 2*log2e): use exp2 directly
                float g  = 2.0f * __builtin_amdgcn_rcpf(
                               1.0f + __builtin_amdgcn_exp2f(-(accg[r] + biasg))) - 1.0f;
                float iv = __builtin_amdgcn_rcpf(
                               1.0f + __builtin_amdgcn_exp2f(-(acci[r] + biasi)));
                float fv = __builtin_amdgcn_rcpf(
                               1.0f + __builtin_amdgcn_exp2f(-(accf[r] + biasf)));
                Aq = fv * Aq + iv * g;
                Fq = fv * Fq;
            }
        }

        // Ordered cross-quad combine (quad q covers t-range q*16..): 2 rounds.
        float Fo = __shfl_xor(Fq, 16, 64);
        float Ao = __shfl_xor(Aq, 16, 64);
        if ((quad & 1) == 0) { Aq = Fo * Aq + Ao; Fq = Fo * Fq; }
        else                 { Aq = Fq * Ao + Aq; Fq = Fq * Fo; }
        Fo = __shfl_xor(Fq, 32, 64);
        Ao = __shfl_xor(Aq, 32, 64);
        if (quad < 2) { Aq = Fo * Aq + Ao; Fq = Fo * Fq; }
        else          { Aq = Fq * Ao + Aq; Fq = Fq * Fo; }

        if (quad == 0) {
            const int idx = (b * NC + c) * H_DIM + h;
            wsF[idx] = Fq;
            wsA[idx] = Aq;
        }

        // ---- publish next chunk into the other buffer, single barrier
        if (j + 1 < CPB) {
            short* fw = frag[(j + 1) & 1];  // its readers finished at barrier j-1
#pragma unroll
            for (int kq = 0; kq < 2; ++kq) {
                const int kk = kk0 + kq;
                float a[8] = {px[2 * kq].x,     px[2 * kq].y,
                              px[2 * kq].z,     px[2 * kq].w,
                              px[2 * kq + 1].x, px[2 * kq + 1].y,
                              px[2 * kq + 1].z, px[2 * kq + 1].w};
                *(bf16x8*)(fw + (((mt_s * 4 + kk) * 64) + L) * 8) = cvt8(a);
            }
            __syncthreads();  // publish frag[(j+1)&1]
        }
    }
}

// Pass 2: fold NC chunk-affines -> c_fin; o-gate at t=T-1 (fp32 dot);
// h_fin = o*tanh(c); classifier + log_softmax. One block per batch.
__global__ void finish_kernel(const float* __restrict__ x,
    const float* __restrict__ w_io, const float* __restrict__ b_o,
    const float* __restrict__ fc1_w, const float* __restrict__ fc1_b,
    const float* __restrict__ fc2_w, const float* __restrict__ fc2_b,
    const float* __restrict__ wsF, const float* __restrict__ wsA,
    float* __restrict__ out)
{
    const int b = blockIdx.x;
    const int h = threadIdx.x;  // 128 threads
    __shared__ float hf[H_DIM];
    __shared__ float z1[FC_DIM];

    float c = 0.0f;
#pragma unroll
    for (int nc = 0; nc < NC; ++nc) {
        const int idx = (b * NC + nc) * H_DIM + h;
        c = wsF[idx] * c + wsA[idx];
    }
    const float* xl = x + ((size_t)(T_DIM - 1) * B_DIM + b) * I_DIM;
    const float* wo = w_io + ((size_t)b * H_DIM + h) * I_DIM;
    float acc = b_o[b * H_DIM + h];
#pragma unroll 8
    for (int i = 0; i < I_DIM; i += 4) {
        float4 xa = *(const float4*)(xl + i);
        float4 wa = *(const float4*)(wo + i);
        acc += xa.x * wa.x + xa.y * wa.y + xa.z * wa.z + xa.w * wa.w;
    }
    const float o = 1.0f / (1.0f + expf(-acc));
    hf[h] = o * tanhf(c);
    __syncthreads();

    if (h < FC_DIM) {
        float a = fc1_b[h];
        const float* w1 = fc1_w + h * H_DIM;
        for (int i = 0; i < H_DIM; ++i) a += w1[i] * hf[i];
        z1[h] = tanhf(a);
    }
    __syncthreads();

    if (h == 0) {
        float z0 = fc2_b[0], zo1 = fc2_b[1];
        for (int j = 0; j < FC_DIM; ++j) {
            z0  += fc2_w[j] * z1[j];
            zo1 += fc2_w[FC_DIM + j] * z1[j];
        }
        const float m = fmaxf(z0, zo1);
        const float lse = m + logf(expf(z0 - m) + expf(zo1 - m));
        out[b * O_DIM + 0] = z0 - lse;
        out[b * O_DIM + 1] = zo1 - lse;
    }
}

extern "C" void kernel_launch(void* const* d_in, const int* in_sizes, int n_in,
                              void* d_out, int out_size, void* d_ws, size_t ws_size,
                              hipStream_t stream) {
    const float* x     = (const float*)d_in[0];
    const float* w_ig  = (const float*)d_in[1];
    const float* w_ii  = (const float*)d_in[2];
    const float* w_if  = (const float*)d_in[3];
    const float* w_io  = (const float*)d_in[4];
    // d_in[5..8] = w_hg/w_hi/w_hf/w_ho multiply a zero hidden state -> skipped
    const float* b_g   = (const float*)d_in[9];
    const float* b_i   = (const float*)d_in[10];
    const float* b_f   = (const float*)d_in[11];
    const float* b_o   = (const float*)d_in[12];
    const float* fc1_w = (const float*)d_in[13];
    const float* fc1_b = (const float*)d_in[14];
    const float* fc2_w = (const float*)d_in[15];
    const float* fc2_b = (const float*)d_in[16];

    // Workspace: wg/wi/wf bf16 (3 x 2 MB) + wsF/wsA (2 x 1 MB)
    const size_t NW = (size_t)B_DIM * H_DIM * I_DIM;    // 1,048,576
    short* wgc = (short*)d_ws;
    short* wic = wgc + NW;
    short* wfc = wic + NW;
    float* wsF = (float*)(wfc + NW);
    float* wsA = wsF + (size_t)B_DIM * NC * H_DIM;
    float* out = (float*)d_out;

    convert_w_kernel<<<dim3(NW / (256 * 8), 3), 256, 0, stream>>>(
        w_ig, w_ii, w_if, wgc, wic, wfc);

    // bid = cp*64 + b (b-minor => per-b weight reuse within an XCD)
    gates_scan_kernel<<<dim3(B_DIM * NC / CPB), 512, 0, stream>>>(
        x, wgc, wic, wfc, b_g, b_i, b_f, wsF, wsA);

    finish_kernel<<<B_DIM, 128, 0, stream>>>(x, w_io, b_o, fc1_w, fc1_b,
                                             fc2_w, fc2_b, wsF, wsA, out);
}

// Round 5
// 160.820 us; speedup vs baseline: 1.6063x; 1.6063x over previous
//
#include <hip/hip_runtime.h>
#include <hip/hip_bf16.h>
#include <cstddef>

#define T_DIM 2048
#define B_DIM 64
#define I_DIM 128
#define H_DIM 128
#define FC_DIM 32
#define O_DIM 2

#define NC 32                // time chunks (parallel affine scan)
#define TC (T_DIM / NC)      // 64 timesteps per chunk
#define MT 4                 // 4 m-tiles of 16 t per chunk
#define CPB 2                // chunks per block -> grid 1024 = 4 blocks/CU

#define LOG2E  1.44269504088896f
#define LOG2E2 2.88539008177793f

typedef __attribute__((ext_vector_type(8))) short bf16x8;
typedef __attribute__((ext_vector_type(4))) float f32x4;

// packed fp32x8 -> bf16x8 (RNE) via v_cvt_pk_bf16_f32
__device__ __forceinline__ bf16x8 cvt8(const float* __restrict__ p) {
    union { bf16x8 v; __hip_bfloat162 h2[4]; } u;
#pragma unroll
    for (int j = 0; j < 4; ++j) {
        float2 f2 = {p[2 * j], p[2 * j + 1]};
        u.h2[j] = __float22bfloat162_rn(f2);
    }
    return u.v;
}

// Pass 0: gate weights fp32 -> bf16, pre-scaled by log2e factors so the
// gates kernel can use exp2 directly. Layout preserved [b][h][i].
__global__ void convert_w_kernel(const float* __restrict__ wg,
                                 const float* __restrict__ wi,
                                 const float* __restrict__ wf,
                                 short* __restrict__ og,
                                 short* __restrict__ oi,
                                 short* __restrict__ of)
{
    const float* src = (blockIdx.y == 0) ? wg : (blockIdx.y == 1) ? wi : wf;
    short* dst       = (blockIdx.y == 0) ? og : (blockIdx.y == 1) ? oi : of;
    const float scale = (blockIdx.y == 0) ? LOG2E2 : LOG2E;
    const size_t idx = ((size_t)blockIdx.x * 256 + threadIdx.x) * 8;
    float4 u0 = *(const float4*)(src + idx);
    float4 u1 = *(const float4*)(src + idx + 4);
    float a[8] = {u0.x * scale, u0.y * scale, u0.z * scale, u0.w * scale,
                  u1.x * scale, u1.y * scale, u1.z * scale, u1.w * scale};
    *(bf16x8*)(dst + idx) = cvt8(a);
}

// Pass 1: one block per (b, chunk-pair), 8 waves covering all 128 h.
// Grid = 1024 = 4 blocks/CU. Occupancy comes from the NATURAL ~52-VGPR
// allocation (<=64 -> 8 waves/SIMD hardware step), NOT from a forced
// launch_bounds min-waves: R4 proved launch_bounds(512,8) makes the
// allocator target 32 VGPRs and spill Bg/Bi/Bf+px to scratch
// (WRITE_SIZE 1->149 MB, FETCH 56->225 MB, 137 us). launch_bounds(512,4)
// keeps the R1-R3 allocation (52 VGPR, no spill) while grid 1024 supplies
// 32 waves/CU residency. LDS 4 x 32 KB = 128 <= 160 KB.
// Double-buffered LDS frags -> ONE barrier per chunk:
//   iter j: issue x loads for chunk c+1 (px regs)
//           compute chunk c from frag[j&1]        (global latency hides here)
//           cvt+write px -> frag[(j+1)&1]         (its readers done at barrier j-1)
//           barrier                               (publishes frag[(j+1)&1])
// Stage duty: wave w handles m-tile (w>>1), kk pair (w&1)*2+{0,1} -> px = 16 VGPR.
// m-row -> t map within chunk: t = (m>>2)*16 + mt*4 + (m&3); D rows
// (row = quad*4 + r) give quad q the t-range [q*16, q*16+16).
__global__ __launch_bounds__(512, 4)
void gates_scan_kernel(const float* __restrict__ x,
    const short* __restrict__ wg, const short* __restrict__ wi,
    const short* __restrict__ wf,
    const float* __restrict__ b_g, const float* __restrict__ b_i,
    const float* __restrict__ b_f,
    float* __restrict__ wsF, float* __restrict__ wsA)
{
    // frag[buf][mt][kk][lane][8 shorts] = 2 * 4*4*64*8 shorts = 2 * 16 KB
    __shared__ short frag[2][MT * 4 * 64 * 8];

    const int L    = threadIdx.x & 63;
    const int wv   = threadIdx.x >> 6;   // 0..7
    const int col  = L & 15;
    const int quad = L >> 4;
    const int bid  = blockIdx.x;
    const int b    = bid & (B_DIM - 1);  // b-minor: same-b blocks -> same XCD
    const int cp   = bid >> 6;           // 0..15 chunk-pair index

    // stage duty for this wave
    const int mt_s = wv >> 1;            // m-tile staged by this wave
    const int kk0  = (wv & 1) * 2;       // first of 2 kk slices
    const int tl_s = (col >> 2) * 16 + mt_s * 4 + (col & 3);  // t within chunk

    // ---- weight fragments for this wave's 16 h columns: h = wv*16 + col
    const int h = wv * 16 + col;
    bf16x8 Bg[4], Bi[4], Bf[4];
    {
        const size_t wo = ((size_t)b * H_DIM + h) * I_DIM + quad * 8;
#pragma unroll
        for (int kk = 0; kk < 4; ++kk) {
            Bg[kk] = *(const bf16x8*)(wg + wo + kk * 32);
            Bi[kk] = *(const bf16x8*)(wi + wo + kk * 32);
            Bf[kk] = *(const bf16x8*)(wf + wo + kk * 32);
        }
    }
    const float biasg = b_g[b * H_DIM + h] * LOG2E2;
    const float biasi = b_i[b * H_DIM + h] * LOG2E;
    const float biasf = b_f[b * H_DIM + h] * LOG2E;

    // ---- prologue: stage chunk cp*CPB into frag[0]
    {
        const float* xp = x + ((size_t)(cp * CPB * TC + tl_s) * B_DIM + b) * I_DIM;
#pragma unroll
        for (int kq = 0; kq < 2; ++kq) {
            const int kk = kk0 + kq;
            const int i0 = quad * 8 + kk * 32;
            float4 u0 = *(const float4*)(xp + i0);
            float4 u1 = *(const float4*)(xp + i0 + 4);
            float a[8] = {u0.x, u0.y, u0.z, u0.w, u1.x, u1.y, u1.z, u1.w};
            *(bf16x8*)(&frag[0][(((mt_s * 4 + kk) * 64) + L) * 8]) = cvt8(a);
        }
    }
    __syncthreads();

    float4 px[4];  // in-flight x for next chunk (16 VGPRs)

#pragma unroll
    for (int j = 0; j < CPB; ++j) {
        const int c = cp * CPB + j;
        const short* fr = frag[j & 1];

        // issue next chunk's x loads EARLY -> latency hides under compute
        if (j + 1 < CPB) {
            const float* xp = x + ((size_t)((c + 1) * TC + tl_s) * B_DIM + b) * I_DIM;
#pragma unroll
            for (int kq = 0; kq < 2; ++kq) {
                const int i0 = quad * 8 + (kk0 + kq) * 32;
                px[2 * kq]     = *(const float4*)(xp + i0);
                px[2 * kq + 1] = *(const float4*)(xp + i0 + 4);
            }
        }

        // ---- compute chunk c: MFMA + activations + per-quad scan
        float Fq = 1.0f, Aq = 0.0f;
#pragma unroll
        for (int mt = 0; mt < MT; ++mt) {
            bf16x8 ah[4];
#pragma unroll
            for (int kk = 0; kk < 4; ++kk)
                ah[kk] = *(const bf16x8*)(fr + (((mt * 4 + kk) * 64) + L) * 8);
            f32x4 accg = {0.f, 0.f, 0.f, 0.f};
            f32x4 acci = {0.f, 0.f, 0.f, 0.f};
            f32x4 accf = {0.f, 0.f, 0.f, 0.f};
#pragma unroll
            for (int kk = 0; kk < 4; ++kk) {
                accg = __builtin_amdgcn_mfma_f32_16x16x32_bf16(ah[kk], Bg[kk], accg, 0, 0, 0);
                acci = __builtin_amdgcn_mfma_f32_16x16x32_bf16(ah[kk], Bi[kk], acci, 0, 0, 0);
                accf = __builtin_amdgcn_mfma_f32_16x16x32_bf16(ah[kk], Bf[kk], accf, 0, 0, 0);
            }
            // D row = quad*4 + r -> t = quad*16 + mt*4 + r (consecutive per quad)
#pragma unroll
            for (int r = 0; r < 4; ++r) {
                // preacts pre-scaled by log2e (g by 2*log2e): use exp2 directly
                float g  = 2.0f * __builtin_amdgcn_rcpf(
                               1.0f + __builtin_amdgcn_exp2f(-(accg[r] + biasg))) - 1.0f;
                float iv = __builtin_amdgcn_rcpf(
                               1.0f + __builtin_amdgcn_exp2f(-(acci[r] + biasi)));
                float fv = __builtin_amdgcn_rcpf(
                               1.0f + __builtin_amdgcn_exp2f(-(accf[r] + biasf)));
                Aq = fv * Aq + iv * g;
                Fq = fv * Fq;
            }
        }

        // Ordered cross-quad combine (quad q covers t-range q*16..): 2 rounds.
        float Fo = __shfl_xor(Fq, 16, 64);
        float Ao = __shfl_xor(Aq, 16, 64);
        if ((quad & 1) == 0) { Aq = Fo * Aq + Ao; Fq = Fo * Fq; }
        else                 { Aq = Fq * Ao + Aq; Fq = Fq * Fo; }
        Fo = __shfl_xor(Fq, 32, 64);
        Ao = __shfl_xor(Aq, 32, 64);
        if (quad < 2) { Aq = Fo * Aq + Ao; Fq = Fo * Fq; }
        else          { Aq = Fq * Ao + Aq; Fq = Fq * Fo; }

        if (quad == 0) {
            const int idx = (b * NC + c) * H_DIM + h;
            wsF[idx] = Fq;
            wsA[idx] = Aq;
        }

        // ---- publish next chunk into the other buffer, single barrier
        if (j + 1 < CPB) {
            short* fw = frag[(j + 1) & 1];  // its readers finished at barrier j-1
#pragma unroll
            for (int kq = 0; kq < 2; ++kq) {
                const int kk = kk0 + kq;
                float a[8] = {px[2 * kq].x,     px[2 * kq].y,
                              px[2 * kq].z,     px[2 * kq].w,
                              px[2 * kq + 1].x, px[2 * kq + 1].y,
                              px[2 * kq + 1].z, px[2 * kq + 1].w};
                *(bf16x8*)(fw + (((mt_s * 4 + kk) * 64) + L) * 8) = cvt8(a);
            }
            __syncthreads();  // publish frag[(j+1)&1]
        }
    }
}

// Pass 2: fold NC chunk-affines -> c_fin; o-gate at t=T-1 (fp32 dot);
// h_fin = o*tanh(c); classifier + log_softmax. One block per batch.
__global__ void finish_kernel(const float* __restrict__ x,
    const float* __restrict__ w_io, const float* __restrict__ b_o,
    const float* __restrict__ fc1_w, const float* __restrict__ fc1_b,
    const float* __restrict__ fc2_w, const float* __restrict__ fc2_b,
    const float* __restrict__ wsF, const float* __restrict__ wsA,
    float* __restrict__ out)
{
    const int b = blockIdx.x;
    const int h = threadIdx.x;  // 128 threads
    __shared__ float hf[H_DIM];
    __shared__ float z1[FC_DIM];

    float c = 0.0f;
#pragma unroll
    for (int nc = 0; nc < NC; ++nc) {
        const int idx = (b * NC + nc) * H_DIM + h;
        c = wsF[idx] * c + wsA[idx];
    }
    const float* xl = x + ((size_t)(T_DIM - 1) * B_DIM + b) * I_DIM;
    const float* wo = w_io + ((size_t)b * H_DIM + h) * I_DIM;
    float acc = b_o[b * H_DIM + h];
#pragma unroll 8
    for (int i = 0; i < I_DIM; i += 4) {
        float4 xa = *(const float4*)(xl + i);
        float4 wa = *(const float4*)(wo + i);
        acc += xa.x * wa.x + xa.y * wa.y + xa.z * wa.z + xa.w * wa.w;
    }
    const float o = 1.0f / (1.0f + expf(-acc));
    hf[h] = o * tanhf(c);
    __syncthreads();

    if (h < FC_DIM) {
        float a = fc1_b[h];
        const float* w1 = fc1_w + h * H_DIM;
        for (int i = 0; i < H_DIM; ++i) a += w1[i] * hf[i];
        z1[h] = tanhf(a);
    }
    __syncthreads();

    if (h == 0) {
        float z0 = fc2_b[0], zo1 = fc2_b[1];
        for (int j = 0; j < FC_DIM; ++j) {
            z0  += fc2_w[j] * z1[j];
            zo1 += fc2_w[FC_DIM + j] * z1[j];
        }
        const float m = fmaxf(z0, zo1);
        const float lse = m + logf(expf(z0 - m) + expf(zo1 - m));
        out[b * O_DIM + 0] = z0 - lse;
        out[b * O_DIM + 1] = zo1 - lse;
    }
}

extern "C" void kernel_launch(void* const* d_in, const int* in_sizes, int n_in,
                              void* d_out, int out_size, void* d_ws, size_t ws_size,
                              hipStream_t stream) {
    const float* x     = (const float*)d_in[0];
    const float* w_ig  = (const float*)d_in[1];
    const float* w_ii  = (const float*)d_in[2];
    const float* w_if  = (const float*)d_in[3];
    const float* w_io  = (const float*)d_in[4];
    // d_in[5..8] = w_hg/w_hi/w_hf/w_ho multiply a zero hidden state -> skipped
    const float* b_g   = (const float*)d_in[9];
    const float* b_i   = (const float*)d_in[10];
    const float* b_f   = (const float*)d_in[11];
    const float* b_o   = (const float*)d_in[12];
    const float* fc1_w = (const float*)d_in[13];
    const float* fc1_b = (const float*)d_in[14];
    const float* fc2_w = (const float*)d_in[15];
    const float* fc2_b = (const float*)d_in[16];

    // Workspace: wg/wi/wf bf16 (3 x 2 MB) + wsF/wsA (2 x 1 MB)
    const size_t NW = (size_t)B_DIM * H_DIM * I_DIM;    // 1,048,576
    short* wgc = (short*)d_ws;
    short* wic = wgc + NW;
    short* wfc = wic + NW;
    float* wsF = (float*)(wfc + NW);
    float* wsA = wsF + (size_t)B_DIM * NC * H_DIM;
    float* out = (float*)d_out;

    convert_w_kernel<<<dim3(NW / (256 * 8), 3), 256, 0, stream>>>(
        w_ig, w_ii, w_if, wgc, wic, wfc);

    // bid = cp*64 + b (b-minor => per-b weight reuse within an XCD)
    gates_scan_kernel<<<dim3(B_DIM * NC / CPB), 512, 0, stream>>>(
        x, wgc, wic, wfc, b_g, b_i, b_f, wsF, wsA);

    finish_kernel<<<B_DIM, 128, 0, stream>>>(x, w_io, b_o, fc1_w, fc1_b,
                                             fc2_w, fc2_b, wsF, wsA, out);
}

// Round 6
// 157.556 us; speedup vs baseline: 1.6396x; 1.0207x over previous
//
#include <hip/hip_runtime.h>
#include <hip/hip_bf16.h>
#include <cstddef>

#define T_DIM 2048
#define B_DIM 64
#define I_DIM 128
#define H_DIM 128
#define FC_DIM 32
#define O_DIM 2

#define NC 16                // time chunks (parallel affine scan)
#define TC (T_DIM / NC)      // 128 timesteps per chunk
#define MT 8                 // 8 m-tiles of 16 t per chunk

#define LOG2E  1.44269504088896f
#define LOG2E2 2.88539008177793f

typedef __attribute__((ext_vector_type(8))) short bf16x8;
typedef __attribute__((ext_vector_type(4))) float f32x4;

// packed fp32x8 -> bf16x8 (RNE) via v_cvt_pk_bf16_f32
__device__ __forceinline__ bf16x8 cvt8(const float* __restrict__ p) {
    union { bf16x8 v; __hip_bfloat162 h2[4]; } u;
#pragma unroll
    for (int j = 0; j < 4; ++j) {
        float2 f2 = {p[2 * j], p[2 * j + 1]};
        u.h2[j] = __float22bfloat162_rn(f2);
    }
    return u.v;
}

// Pass 0: gate weights fp32 -> bf16, pre-scaled by log2e factors so the
// gates kernel can use exp2 directly. Layout preserved [b][h][i].
__global__ void convert_w_kernel(const float* __restrict__ wg,
                                 const float* __restrict__ wi,
                                 const float* __restrict__ wf,
                                 short* __restrict__ og,
                                 short* __restrict__ oi,
                                 short* __restrict__ of)
{
    const float* src = (blockIdx.y == 0) ? wg : (blockIdx.y == 1) ? wi : wf;
    short* dst       = (blockIdx.y == 0) ? og : (blockIdx.y == 1) ? oi : of;
    const float scale = (blockIdx.y == 0) ? LOG2E2 : LOG2E;
    const size_t idx = ((size_t)blockIdx.x * 256 + threadIdx.x) * 8;
    float4 u0 = *(const float4*)(src + idx);
    float4 u1 = *(const float4*)(src + idx + 4);
    float a[8] = {u0.x * scale, u0.y * scale, u0.z * scale, u0.w * scale,
                  u1.x * scale, u1.y * scale, u1.z * scale, u1.w * scale};
    *(bf16x8*)(dst + idx) = cvt8(a);
}

// Pass 1: one block per (b, chunk), 8 waves covering all 128 h.
// (Round-0 structure restored verbatim: across R1-R5, fusion, CPB-pipelining,
// NC=32 resizing, and occupancy forcing all landed at or above this
// structure's total within the ±1.7% noise band of the fill-dominated
// window; this remains the measured-best artifact at 156.3-156.7 us.)
// Phase A: waves cooperatively convert the chunk's x slice (fp32, read once)
//          into bf16 MFMA A-fragments in LDS (fragment-order layout ->
//          conflict-free b128 writes & reads).
// Phase B: per m-tile: 4 ds_read_b128, 12 MFMA, exp2-based activations,
//          per-quad affine scan; cross-quad combine at end.
// m-row -> t map within chunk: t(m) = (m>>2)*32 + mt*4 + (m&3); D rows
// (row = quad*4 + r) give each quad 4 consecutive t; quad q owns [q*32, q*32+32).
__global__ __launch_bounds__(512, 4)
void gates_scan_kernel(const float* __restrict__ x,
    const short* __restrict__ wg, const short* __restrict__ wi,
    const short* __restrict__ wf,
    const float* __restrict__ b_g, const float* __restrict__ b_i,
    const float* __restrict__ b_f,
    float* __restrict__ wsF, float* __restrict__ wsA)
{
    // frag[mt][kk][lane][8 shorts] = 8*4*64*8 shorts = 32 KB
    __shared__ short frag[MT * 4 * 64 * 8];

    const int L    = threadIdx.x & 63;
    const int wv   = threadIdx.x >> 6;   // 0..7: conversion mt / compute h-group
    const int col  = L & 15;
    const int quad = L >> 4;
    const int bid  = blockIdx.x;
    const int b     = bid & (B_DIM - 1);  // b-minor: same-b blocks 64 apart -> same XCD
    const int chunk = bid >> 6;

    // ---- weight fragments for this wave's 16 h columns: h = wv*16 + col
    const int h = wv * 16 + col;
    bf16x8 Bg[4], Bi[4], Bf[4];
    {
        const size_t wo = ((size_t)b * H_DIM + h) * I_DIM + quad * 8;
#pragma unroll
        for (int kk = 0; kk < 4; ++kk) {
            Bg[kk] = *(const bf16x8*)(wg + wo + kk * 32);
            Bi[kk] = *(const bf16x8*)(wi + wo + kk * 32);
            Bf[kk] = *(const bf16x8*)(wf + wo + kk * 32);
        }
    }
    const float biasg = b_g[b * H_DIM + h] * LOG2E2;
    const float biasi = b_i[b * H_DIM + h] * LOG2E;
    const float biasf = b_f[b * H_DIM + h] * LOG2E;

    // ---- Phase A: convert m-tile mt = wv into LDS fragments
    {
        const int mt = wv;
        const int tl = (col >> 2) * 32 + mt * 4 + (col & 3);  // t within chunk
        const float* xp = x + ((size_t)(chunk * TC + tl) * B_DIM + b) * I_DIM;
#pragma unroll
        for (int kk = 0; kk < 4; ++kk) {
            const int i0 = quad * 8 + kk * 32;
            float4 u0 = *(const float4*)(xp + i0);
            float4 u1 = *(const float4*)(xp + i0 + 4);
            float a[8] = {u0.x, u0.y, u0.z, u0.w, u1.x, u1.y, u1.z, u1.w};
            *(bf16x8*)(frag + (((mt * 4 + kk) * 64) + L) * 8) = cvt8(a);
        }
    }
    __syncthreads();

    // ---- Phase B: MFMA + activations + per-quad scan
    float Fq = 1.0f, Aq = 0.0f;
#pragma unroll 2
    for (int mt = 0; mt < MT; ++mt) {
        bf16x8 ah[4];
#pragma unroll
        for (int kk = 0; kk < 4; ++kk)
            ah[kk] = *(const bf16x8*)(frag + (((mt * 4 + kk) * 64) + L) * 8);
        f32x4 accg = {0.f, 0.f, 0.f, 0.f};
        f32x4 acci = {0.f, 0.f, 0.f, 0.f};
        f32x4 accf = {0.f, 0.f, 0.f, 0.f};
#pragma unroll
        for (int kk = 0; kk < 4; ++kk) {
            accg = __builtin_amdgcn_mfma_f32_16x16x32_bf16(ah[kk], Bg[kk], accg, 0, 0, 0);
            acci = __builtin_amdgcn_mfma_f32_16x16x32_bf16(ah[kk], Bi[kk], acci, 0, 0, 0);
            accf = __builtin_amdgcn_mfma_f32_16x16x32_bf16(ah[kk], Bf[kk], accf, 0, 0, 0);
        }
        // D row = quad*4 + r -> t = quad*32 + mt*4 + r (consecutive per quad)
#pragma unroll
        for (int r = 0; r < 4; ++r) {
            // preacts pre-scaled by log2e (g by 2*log2e): use exp2 directly
            float g  = 2.0f * __builtin_amdgcn_rcpf(
                           1.0f + __builtin_amdgcn_exp2f(-(accg[r] + biasg))) - 1.0f;
            float iv = __builtin_amdgcn_rcpf(
                           1.0f + __builtin_amdgcn_exp2f(-(acci[r] + biasi)));
            float fv = __builtin_amdgcn_rcpf(
                           1.0f + __builtin_amdgcn_exp2f(-(accf[r] + biasf)));
            Aq = fv * Aq + iv * g;
            Fq = fv * Fq;
        }
    }

    // Ordered cross-quad combine (quad q covers t-range q*32..): 2 rounds.
    float Fo = __shfl_xor(Fq, 16, 64);
    float Ao = __shfl_xor(Aq, 16, 64);
    if ((quad & 1) == 0) { Aq = Fo * Aq + Ao; Fq = Fo * Fq; }
    else                 { Aq = Fq * Ao + Aq; Fq = Fq * Fo; }
    Fo = __shfl_xor(Fq, 32, 64);
    Ao = __shfl_xor(Aq, 32, 64);
    if (quad < 2) { Aq = Fo * Aq + Ao; Fq = Fo * Fq; }
    else          { Aq = Fq * Ao + Aq; Fq = Fq * Fo; }

    if (quad == 0) {
        const int idx = (b * NC + chunk) * H_DIM + h;
        wsF[idx] = Fq;
        wsA[idx] = Aq;
    }
}

// Pass 2: fold NC chunk-affines -> c_fin; o-gate at t=T-1 (fp32 dot);
// h_fin = o*tanh(c); classifier + log_softmax. One block per batch.
__global__ void finish_kernel(const float* __restrict__ x,
    const float* __restrict__ w_io, const float* __restrict__ b_o,
    const float* __restrict__ fc1_w, const float* __restrict__ fc1_b,
    const float* __restrict__ fc2_w, const float* __restrict__ fc2_b,
    const float* __restrict__ wsF, const float* __restrict__ wsA,
    float* __restrict__ out)
{
    const int b = blockIdx.x;
    const int h = threadIdx.x;  // 128 threads
    __shared__ float hf[H_DIM];
    __shared__ float z1[FC_DIM];

    float c = 0.0f;
#pragma unroll
    for (int nc = 0; nc < NC; ++nc) {
        const int idx = (b * NC + nc) * H_DIM + h;
        c = wsF[idx] * c + wsA[idx];
    }
    const float* xl = x + ((size_t)(T_DIM - 1) * B_DIM + b) * I_DIM;
    const float* wo = w_io + ((size_t)b * H_DIM + h) * I_DIM;
    float acc = b_o[b * H_DIM + h];
#pragma unroll 8
    for (int i = 0; i < I_DIM; i += 4) {
        float4 xa = *(const float4*)(xl + i);
        float4 wa = *(const float4*)(wo + i);
        acc += xa.x * wa.x + xa.y * wa.y + xa.z * wa.z + xa.w * wa.w;
    }
    const float o = 1.0f / (1.0f + expf(-acc));
    hf[h] = o * tanhf(c);
    __syncthreads();

    if (h < FC_DIM) {
        float a = fc1_b[h];
        const float* w1 = fc1_w + h * H_DIM;
        for (int i = 0; i < H_DIM; ++i) a += w1[i] * hf[i];
        z1[h] = tanhf(a);
    }
    __syncthreads();

    if (h == 0) {
        float z0 = fc2_b[0], zo1 = fc2_b[1];
        for (int j = 0; j < FC_DIM; ++j) {
            z0  += fc2_w[j] * z1[j];
            zo1 += fc2_w[FC_DIM + j] * z1[j];
        }
        const float m = fmaxf(z0, zo1);
        const float lse = m + logf(expf(z0 - m) + expf(zo1 - m));
        out[b * O_DIM + 0] = z0 - lse;
        out[b * O_DIM + 1] = zo1 - lse;
    }
}

extern "C" void kernel_launch(void* const* d_in, const int* in_sizes, int n_in,
                              void* d_out, int out_size, void* d_ws, size_t ws_size,
                              hipStream_t stream) {
    const float* x     = (const float*)d_in[0];
    const float* w_ig  = (const float*)d_in[1];
    const float* w_ii  = (const float*)d_in[2];
    const float* w_if  = (const float*)d_in[3];
    const float* w_io  = (const float*)d_in[4];
    // d_in[5..8] = w_hg/w_hi/w_hf/w_ho multiply a zero hidden state -> skipped
    const float* b_g   = (const float*)d_in[9];
    const float* b_i   = (const float*)d_in[10];
    const float* b_f   = (const float*)d_in[11];
    const float* b_o   = (const float*)d_in[12];
    const float* fc1_w = (const float*)d_in[13];
    const float* fc1_b = (const float*)d_in[14];
    const float* fc2_w = (const float*)d_in[15];
    const float* fc2_b = (const float*)d_in[16];

    // Workspace: wg/wi/wf bf16 (3 x 2 MB) + wsF/wsA (2 x 512 KB)
    const size_t NW = (size_t)B_DIM * H_DIM * I_DIM;    // 1,048,576
    short* wgc = (short*)d_ws;
    short* wic = wgc + NW;
    short* wfc = wic + NW;
    float* wsF = (float*)(wfc + NW);
    float* wsA = wsF + (size_t)B_DIM * NC * H_DIM;
    float* out = (float*)d_out;

    convert_w_kernel<<<dim3(NW / (256 * 8), 3), 256, 0, stream>>>(
        w_ig, w_ii, w_if, wgc, wic, wfc);

    // bid = chunk*64 + b (b-minor => per-b weight reuse within an XCD)
    gates_scan_kernel<<<dim3(B_DIM * NC), 512, 0, stream>>>(
        x, wgc, wic, wfc, b_g, b_i, b_f, wsF, wsA);

    finish_kernel<<<B_DIM, 128, 0, stream>>>(x, w_io, b_o, fc1_w, fc1_b,
                                             fc2_w, fc2_b, wsF, wsA, out);
}